// Round 10
// baseline (308.732 us; speedup 1.0000x reference)
//
#include <hip/hip_runtime.h>

// Segment-mean, 3 dispatches:
//   0. zero_counts: counts=0, ovf[0]=0
//   1. scatter_slots: atomicAdd(&counts[id],1) -> count + slot k;
//      row stored at slots[id*16+k]; rows past 16 (P ~1e-7/seg) -> ovf list.
//   2. gather_mean: 16 lanes per segment-PAIR. BRANCHLESS body: both
//      segments' first 8 slot-rows loaded unconditionally (invalid rows
//      clamped to row 0 = L2-hot, masked off by multiply) -> 16 src loads
//      guaranteed in flight, zero branches for cnt<=8 (98% of segments).
//      Rare tails (cnt>8) loop; cnt>16 reads the (empty) ovf list in-kernel.

#define SLOTS   16
#define OVF_CAP 8192

typedef float f32x4 __attribute__((ext_vector_type(4)));
typedef int   i32x4 __attribute__((ext_vector_type(4)));

__global__ void zero_counts(int* __restrict__ counts, int* __restrict__ ovf, int m4) {
    const int stride = gridDim.x * blockDim.x;
    i32x4* c4 = reinterpret_cast<i32x4*>(counts);
    for (int i = blockIdx.x * blockDim.x + threadIdx.x; i < m4; i += stride)
        c4[i] = (i32x4)(0);
    if (blockIdx.x == 0 && threadIdx.x == 0) ovf[0] = 0;
}

__global__ void scatter_slots(const int* __restrict__ ids,
                              int* __restrict__ counts,
                              int* __restrict__ slots,
                              int* __restrict__ ovf,   // [0]=n_ovf, then (row,id) pairs
                              int n4) {
    const int i = blockIdx.x * blockDim.x + threadIdx.x;
    if (i >= n4) return;
    const i32x4 v = __builtin_nontemporal_load(reinterpret_cast<const i32x4*>(ids) + i);
    const int r0 = i << 2;
    #pragma unroll
    for (int j = 0; j < 4; ++j) {
        const int id = v[j];
        const int k  = atomicAdd(&counts[id], 1);
        if (k < SLOTS) {
            slots[id * SLOTS + k] = r0 + j;
        } else {
            int p = atomicAdd(ovf, 1);
            if (p < OVF_CAP) { ovf[1 + 2 * p] = r0 + j; ovf[2 + 2 * p] = id; }
        }
    }
}

__global__ void gather_mean(const float* __restrict__ src,
                            const int* __restrict__ slots,
                            const int* __restrict__ counts,
                            const int* __restrict__ ovf,
                            float* __restrict__ out, int m) {
    const int t = blockIdx.x * blockDim.x + threadIdx.x;
    const int p = t >> 4;                         // segment PAIR index
    const int q = t & 15;                         // float4 slot: 4 channels
    const int sA = 2 * p, sB = 2 * p + 1;
    if (sB >= m) return;                          // m even -> exact
    const long bA = (long)sA * SLOTS, bB = (long)sB * SLOTS;
    // Address-independent: slot quads + counts issue concurrently.
    const i32x4 xA0 = *reinterpret_cast<const i32x4*>(slots + bA);
    const i32x4 xB0 = *reinterpret_cast<const i32x4*>(slots + bB);
    const i32x4 xA1 = *reinterpret_cast<const i32x4*>(slots + bA + 4);
    const i32x4 xB1 = *reinterpret_cast<const i32x4*>(slots + bB + 4);
    const int2  c2  = *reinterpret_cast<const int2*>(counts + sA);
    const int cA = c2.x, cB = c2.y;
    const int lA = cA < SLOTS ? cA : SLOTS;
    const int lB = cB < SLOTS ? cB : SLOTS;
    const f32x4* s4 = reinterpret_cast<const f32x4*>(src);

    // Branchless: clamp invalid slot-rows to row 0 (stale slot values are
    // never dereferenced), load all 16 unconditionally, mask via multiply.
    // Row-0 dup reads are L2-broadcast — no HBM cost.
    int rA[8], rB[8];
    #pragma unroll
    for (int j = 0; j < 4; ++j) {
        rA[j]     = (lA > j)     ? xA0[j] : 0;
        rA[j + 4] = (lA > j + 4) ? xA1[j] : 0;
        rB[j]     = (lB > j)     ? xB0[j] : 0;
        rB[j + 4] = (lB > j + 4) ? xB1[j] : 0;
    }
    f32x4 vA[8], vB[8];
    #pragma unroll
    for (int j = 0; j < 8; ++j) {                 // 16 loads, no branches between
        vA[j] = s4[(long)rA[j] * 16 + q];
        vB[j] = s4[(long)rB[j] * 16 + q];
    }
    f32x4 aA = (f32x4)(0.f), aB = (f32x4)(0.f);
    #pragma unroll
    for (int j = 0; j < 8; ++j) {
        aA += vA[j] * ((lA > j) ? 1.0f : 0.0f);
        aB += vB[j] * ((lB > j) ? 1.0f : 0.0f);
    }

    if ((lA > 8) | (lB > 8)) {                    // rare tail (P ~2%/segment)
        const int lmax = lA > lB ? lA : lB;
        for (int kk = 8; kk < lmax; kk += 4) {
            const i32x4 yA = *reinterpret_cast<const i32x4*>(slots + bA + kk);
            const i32x4 yB = *reinterpret_cast<const i32x4*>(slots + bB + kk);
            #pragma unroll
            for (int j = 0; j < 4; ++j) {
                const int wA = (lA > kk + j) ? yA[j] : 0;
                const int wB = (lB > kk + j) ? yB[j] : 0;
                aA += s4[(long)wA * 16 + q] * ((lA > kk + j) ? 1.0f : 0.0f);
                aB += s4[(long)wB * 16 + q] * ((lB > kk + j) ? 1.0f : 0.0f);
            }
        }
    }
    if ((cA > SLOTS) | (cB > SLOTS)) {            // ~never: consume ovf list
        int novf = ovf[0];
        if (novf > OVF_CAP) novf = OVF_CAP;
        for (int e = 0; e < novf; ++e) {
            const int row = ovf[1 + 2 * e], id = ovf[2 + 2 * e];
            if (id == sA) aA += s4[(long)row * 16 + q];
            if (id == sB) aB += s4[(long)row * 16 + q];
        }
    }
    aA *= 1.0f / (float)(cA > 1 ? cA : 1);
    aB *= 1.0f / (float)(cB > 1 ? cB : 1);
    __builtin_nontemporal_store(aA, reinterpret_cast<f32x4*>(out) + ((long)sA * 16 + q));
    __builtin_nontemporal_store(aB, reinterpret_cast<f32x4*>(out) + ((long)sB * 16 + q));
}

extern "C" void kernel_launch(void* const* d_in, const int* in_sizes, int n_in,
                              void* d_out, int out_size, void* d_ws, size_t ws_size,
                              hipStream_t stream) {
    const int*   ids = (const int*)d_in[0];
    const float* src = (const float*)d_in[1];
    float*       out = (float*)d_out;

    const int n = in_sizes[0];                   // N = 2097152 (divisible by 4)
    const int m = out_size / 64;                 // M = 524288 (even)

    // Workspace (ints): counts[m] | ovf[1+2*OVF_CAP] | slots[m*SLOTS]
    int* counts = (int*)d_ws;
    int* ovf    = counts + m;
    int* slots  = ovf + (1 + 2 * OVF_CAP);

    zero_counts<<<256, 256, 0, stream>>>(counts, ovf, m >> 2);
    const int n4 = n >> 2;
    scatter_slots<<<(n4 + 255) / 256, 256, 0, stream>>>(ids, counts, slots, ovf, n4);
    const int pairs = m / 2;
    gather_mean<<<(pairs * 16 + 255) / 256, 256, 0, stream>>>(src, slots, counts, ovf, out, m);
}